// Round 17
// baseline (1312.894 us; speedup 1.0000x reference)
//
#include <hip/hip_runtime.h>

// WeatherModel: ConvLSTM encoder-decoder with attention.
// All heavy convs on bf16 MFMA implicit GEMM; independent ops co-scheduled.
// Encoder steady state: ONE dispatch = enc2[k] || enc1[k+1] || attnE[k+2].
// B=4, T_IN=10, T_OUT=5, D=5, M=N=96, H1=64, ATTN=32, SEL=0.

#define PIX  9216
#define NB   4
#define TIN  10
#define TOUT 5
#define ND   5
#define HID  64

typedef __attribute__((ext_vector_type(8))) short bf16x8;
typedef __attribute__((ext_vector_type(4))) float f32x4;

__device__ __forceinline__ float sigmf_(float x) { return 1.0f / (1.0f + __expf(-x)); }
__device__ __forceinline__ float tanhf_(float x) { return 1.0f - 2.0f / (__expf(2.0f * x) + 1.0f); }
__device__ __forceinline__ unsigned short f2bf(float f) {
    unsigned u = __float_as_uint(f);
    unsigned r = u + 0x7FFFu + ((u >> 16) & 1u);
    return (unsigned short)(r >> 16);
}
__device__ __forceinline__ float bf2f(unsigned short u) {
    return __uint_as_float(((unsigned)u) << 16);
}
__device__ __forceinline__ unsigned fmap_(float f) {
    unsigned u = __float_as_uint(f);
    return (u & 0x80000000u) ? ~u : (u | 0x80000000u);
}
__device__ __forceinline__ float funmap_(unsigned v) {
    return __uint_as_float((v & 0x80000000u) ? (v ^ 0x80000000u) : ~v);
}
__device__ __forceinline__ void gload_lds16(const void* g, void* l) {
    __builtin_amdgcn_global_load_lds(
        (const __attribute__((address_space(1))) void*)g,
        (__attribute__((address_space(3))) void*)l, 16, 0, 0);
}

// ---------------------------------------------------------------------------
// cell64 body: XCD swizzle + setprio + global_load_lds staging + af ring-3.
// XCONV: extra K-chunk for a single fp32 input channel (K slots = 9 taps).
// block (64,4); bid in [0,384); LDS 2 x 20480 at smem.
// ---------------------------------------------------------------------------
template <int NCH, bool XCONV>
__device__ __forceinline__ void
cell64_body(char* smem, int bid,
            const unsigned short* __restrict__ inP,
            const unsigned short* __restrict__ wP,
            const float* __restrict__ bias,
            const float* cprev, float* cout,
            const float* __restrict__ zeropg,
            unsigned short* __restrict__ d1, int d1_coff, int d1_ncg,
            unsigned short* __restrict__ d2, int d2_coff, int d2_ncg,
            const float* __restrict__ xim, const unsigned short* __restrict__ wxP)
{
    const int lane = threadIdx.x;
    const int wv   = threadIdx.y;
    const int tid  = wv * 64 + lane;
    const int rid = (bid & 7) * 48 + (bid >> 3);
    const int y = rid % 96, b = rid / 96;
    const int l15 = lane & 15, l4 = lane >> 4;
    const int NCG = NCH * 4;

    const int scg  = tid & 3;
    const int spr0 = tid >> 2;

    auto stage = [&](char* buf, int cc) {
#pragma unroll
        for (int i = 0; i < 5; ++i) {
            int pr = spr0 + i * 64;
            int r = pr / 98;
            int p = pr - r * 98;
            int gy = y - 1 + r, gx = p - 1;
            const void* g = (const void*)zeropg;
            if (pr < 294 && (unsigned)gy < 96u && (unsigned)gx < 96u) {
                int cg = scg ^ ((p >> 1) & 3);
                g = (const void*)(inP + (((size_t)(b * NCG + cc * 4 + cg) * 9216
                                          + gy * 96 + gx) << 3));
            }
            gload_lds16(g, buf + i * 4096 + wv * 1024);
        }
    };

    f32x4 acc[4][6] = {};
    bf16x8 af[3][4];

#pragma unroll
    for (int t0 = 0; t0 < 2; ++t0)
#pragma unroll
        for (int g = 0; g < 4; ++g)
            af[t0][g] = *(const bf16x8*)(wP
                + ((size_t)(t0 * NCH + 0) * 256 + g * 64 + wv * 16 + l15) * 32 + l4 * 8);

    stage(smem, 0);
    __syncthreads();
#pragma unroll
    for (int cc = 0; cc < NCH; ++cc) {
        if (cc + 1 < NCH) stage(smem + ((cc + 1) & 1) * 20480, cc + 1);
        const char* buf = smem + (cc & 1) * 20480;
#pragma unroll
        for (int tap = 0; tap < 9; ++tap) {
            const int T = cc * 9 + tap;
            const int Tp = T + 2;
            if (Tp < NCH * 9) {
                const int cc2 = Tp / 9, tap2 = Tp % 9;
#pragma unroll
                for (int g = 0; g < 4; ++g)
                    af[Tp % 3][g] = *(const bf16x8*)(wP
                        + ((size_t)(tap2 * NCH + cc2) * 256 + g * 64 + wv * 16 + l15) * 32 + l4 * 8);
            }
            const int ky = tap / 3, kx = tap % 3;
            bf16x8 bk[6];
#pragma unroll
            for (int k = 0; k < 6; ++k) {
                int p = k * 16 + kx + l15;
                int slot = l4 ^ ((p >> 1) & 3);
                bk[k] = *(const bf16x8*)(buf + (ky * 98 + p) * 64 + slot * 16);
            }
            __builtin_amdgcn_s_setprio(1);
#pragma unroll
            for (int g = 0; g < 4; ++g)
#pragma unroll
                for (int k = 0; k < 6; ++k)
                    acc[g][k] = __builtin_amdgcn_mfma_f32_16x16x32_bf16(
                        af[T % 3][g], bk[k], acc[g][k], 0, 0, 0);
            __builtin_amdgcn_s_setprio(0);
        }
        if (cc + 1 < NCH) __syncthreads();
    }

    if (XCONV) {
        bf16x8 afx[4];
#pragma unroll
        for (int g = 0; g < 4; ++g)
            afx[g] = *(const bf16x8*)(wxP
                + ((size_t)(g * 64 + wv * 16 + l15)) * 32 + l4 * 8);
        const float* xb = xim + b * PIX;
#pragma unroll
        for (int k = 0; k < 6; ++k) {
            int p = k * 16 + l15;
            bf16x8 bx = { 0, 0, 0, 0, 0, 0, 0, 0 };
#pragma unroll
            for (int j = 0; j < 8; ++j) {
                int tap = l4 * 8 + j;
                if (tap < 9) {
                    int gy = y + tap / 3 - 1, gx = p + tap % 3 - 1;
                    if ((unsigned)gy < 96u && (unsigned)gx < 96u)
                        bx[j] = (short)f2bf(xb[gy * 96 + gx]);
                }
            }
#pragma unroll
            for (int g = 0; g < 4; ++g)
                acc[g][k] = __builtin_amdgcn_mfma_f32_16x16x32_bf16(
                    afx[g], bx, acc[g][k], 0, 0, 0);
        }
    }

#pragma unroll
    for (int r = 0; r < 4; ++r) {
        int hc = wv * 16 + l4 * 4 + r;
        float bi = bias[hc], bff = bias[64 + hc];
        float bo = bias[128 + hc], bg = bias[192 + hc];
#pragma unroll
        for (int k = 0; k < 6; ++k) {
            int px = k * 16 + l15;
            int gpix = y * 96 + px;
            float ii = sigmf_(acc[0][k][r] + bi);
            float ff = sigmf_(acc[1][k][r] + bff);
            float oo = sigmf_(acc[2][k][r] + bo);
            float gg = tanhf_(acc[3][k][r] + bg);
            int cidx = (b * HID + hc) * 9216 + gpix;
            float cn = ff * cprev[cidx] + ii * gg;
            cout[cidx] = cn;
            unsigned short hb = f2bf(oo * tanhf_(cn));
            int ch1 = d1_coff + hc;
            d1[((size_t)(b * d1_ncg + (ch1 >> 3)) * 9216 + gpix) * 8 + (ch1 & 7)] = hb;
            if (d2) {
                int ch2 = d2_coff + hc;
                d2[((size_t)(b * d2_ncg + (ch2 >> 3)) * 9216 + gpix) * 8 + (ch2 & 7)] = hb;
            }
        }
    }
}

// ---------------------------------------------------------------------------
// attn_e body (hidE fused); block (64,4); aid in [0,720).
// ---------------------------------------------------------------------------
__device__ __forceinline__ void
attnE_body(char* smem, int aid,
           const unsigned short* __restrict__ xsp, const unsigned short* __restrict__ wiP,
           const float* __restrict__ h0, const float* __restrict__ c0,
           const float* __restrict__ wh, const float* __restrict__ bh,
           const float* __restrict__ bi, unsigned short* __restrict__ eP)
{
    float* heS = (float*)smem;
    const int lane = threadIdx.x, wvid = threadIdx.y;
    const int tile = aid % 36, k = (aid / 36) % 5, bb = aid / 180;
    const int l15 = lane & 15, l4 = lane >> 4;
    const int tid = wvid * 64 + lane;

    {
        int p = tile * 256 + tid;
        int y = p / 96, x = p - y * 96;
        float hv9[9], cv9[9];
        const float* hp = h0 + bb * PIX;
        const float* cp = c0 + bb * PIX;
#pragma unroll
        for (int t9 = 0; t9 < 9; ++t9) {
            int gy = y + t9 / 3 - 1, gx = x + t9 % 3 - 1;
            bool ok = (unsigned)gy < 96u && (unsigned)gx < 96u;
            hv9[t9] = ok ? hp[gy * 96 + gx] : 0.0f;
            cv9[t9] = ok ? cp[gy * 96 + gx] : 0.0f;
        }
#pragma unroll
        for (int ch = 0; ch < 32; ++ch) {
            float a = bi[ch] + bh[ch];
#pragma unroll
            for (int t9 = 0; t9 < 9; ++t9) {
                a = fmaf(wh[(ch * 2 + 0) * 9 + t9], hv9[t9], a);
                a = fmaf(wh[(ch * 2 + 1) * 9 + t9], cv9[t9], a);
            }
            heS[tid * 33 + ch] = a;
        }
    }

    bf16x8 af[5][2];
#pragma unroll
    for (int j = 0; j < 5; ++j)
#pragma unroll
        for (int m = 0; m < 2; ++m)
            af[j][m] = *(const bf16x8*)(wiP + ((size_t)(j * 32 + m * 16 + l15)) * 32 + l4 * 8);

    const unsigned short* xb = xsp + (size_t)(bb * ND + k) * PIX * 16;
    const int p0 = tile * 256 + wvid * 64;

    f32x4 acc[4][2] = {};
#pragma unroll
    for (int nf = 0; nf < 4; ++nf) {
        int p = p0 + nf * 16 + l15;
        int y = p / 96, x = p - y * 96;
#pragma unroll
        for (int j = 0; j < 5; ++j) {
            int tp = 2 * j + (l4 >> 1);
            bf16x8 bk = { 0, 0, 0, 0, 0, 0, 0, 0 };
            if (tp < 9) {
                int gy = y + tp / 3 - 1, gx = x + tp % 3 - 1;
                if ((unsigned)gy < 96u && (unsigned)gx < 96u)
                    bk = *(const bf16x8*)(xb + ((size_t)(gy * 96 + gx)) * 16 + (l4 & 1) * 8);
            }
            acc[nf][0] = __builtin_amdgcn_mfma_f32_16x16x32_bf16(af[j][0], bk, acc[nf][0], 0, 0, 0);
            acc[nf][1] = __builtin_amdgcn_mfma_f32_16x16x32_bf16(af[j][1], bk, acc[nf][1], 0, 0, 0);
        }
    }

    __syncthreads();

#pragma unroll
    for (int nf = 0; nf < 4; ++nf) {
        int p = p0 + nf * 16 + l15;
        int pl = wvid * 64 + nf * 16 + l15;
        const float* hrow = &heS[pl * 33];
#pragma unroll
        for (int m = 0; m < 2; ++m) {
            ushort4 o;
            o.x = f2bf(tanhf_(acc[nf][m][0] + hrow[m * 16 + l4 * 4 + 0]));
            o.y = f2bf(tanhf_(acc[nf][m][1] + hrow[m * 16 + l4 * 4 + 1]));
            o.z = f2bf(tanhf_(acc[nf][m][2] + hrow[m * 16 + l4 * 4 + 2]));
            o.w = f2bf(tanhf_(acc[nf][m][3] + hrow[m * 16 + l4 * 4 + 3]));
            *(ushort4*)(eP + ((size_t)(bb * ND + k) * PIX + p) * 32 + m * 16 + l4 * 4) = o;
        }
    }
}

// ---------------------------------------------------------------------------
__device__ __forceinline__ void
alpha_body(char* smem, int aid,
           const unsigned short* __restrict__ eP, const float* __restrict__ wvv,
           const float* __restrict__ bv, float* __restrict__ alpha,
           unsigned* __restrict__ msl)
{
    const int tid = threadIdx.y * 64 + threadIdx.x;
    const int tile = aid % 36, k = (aid / 36) % 5, bb = aid / 180;
    int p = tile * 256 + tid;
    int y = p / 96, x = p - y * 96;
    const unsigned short* eb = eP + (size_t)(bb * ND + k) * PIX * 32;
    float acc = bv[0];
#pragma unroll
    for (int ky = 0; ky < 3; ++ky) {
        int gy = y + ky - 1;
        if ((unsigned)gy >= 96u) continue;
#pragma unroll
        for (int kx = 0; kx < 3; ++kx) {
            int gx = x + kx - 1;
            if ((unsigned)gx >= 96u) continue;
            int tap = ky * 3 + kx;
            const unsigned short* ee = eb + ((size_t)(gy * 96 + gx)) * 32;
#pragma unroll
            for (int cg = 0; cg < 4; ++cg) {
                bf16x8 ev = *(const bf16x8*)(ee + cg * 8);
#pragma unroll
                for (int jj = 0; jj < 8; ++jj)
                    acc = fmaf(wvv[(cg * 8 + jj) * 9 + tap], bf2f((unsigned short)ev[jj]), acc);
            }
        }
    }
    alpha[(size_t)(bb * ND + k) * PIX + p] = acc;

    float* s = (float*)smem;
    s[tid] = acc;
    __syncthreads();
    for (int st = 128; st > 0; st >>= 1) {
        if (tid < st) s[tid] = fmaxf(s[tid], s[tid + st]);
        __syncthreads();
    }
    if (tid == 0) atomicMax(msl, fmap_(s[0]));
}

// ---------------------------------------------------------------------------
// dec2+tcnn body; block (64,4); did in [0,576).
// ---------------------------------------------------------------------------
__device__ __forceinline__ void
dec2_body(int did,
          const unsigned short* __restrict__ inP, int ncg, int cgbase,
          const float* __restrict__ hprev, const float* cprev,
          const unsigned short* __restrict__ wm, const float* __restrict__ w2,
          const float* __restrict__ bias,
          const float* __restrict__ tw, const float* __restrict__ tb,
          const float* __restrict__ yprev,
          float* __restrict__ ynext, float* __restrict__ hcarry,
          float* __restrict__ outp, float* cout)
{
    const int wv = threadIdx.y, lane = threadIdx.x;
    const int l15 = lane & 15, l4 = lane >> 4;
    const int bx = did % 144, b = did / 144;
    const int p0 = (bx * 4 + wv) * 16;
    const int y = p0 / 96, xbase = p0 - y * 96;
    const int x = xbase + l15;

    f32x4 acc = {0.f, 0.f, 0.f, 0.f};
#pragma unroll
    for (int ky = 0; ky < 3; ++ky) {
        int gy = y + ky - 1;
        bool oky = (unsigned)gy < 96u;
#pragma unroll
        for (int kx = 0; kx < 3; ++kx) {
            const int tap = ky * 3 + kx;
            int gx = x + kx - 1;
            bool ok = oky && ((unsigned)gx < 96u);
#pragma unroll
            for (int cc = 0; cc < 2; ++cc) {
                bf16x8 a = *(const bf16x8*)(wm + ((size_t)(tap * 2 + cc) * 16 + l15) * 32 + l4 * 8);
                bf16x8 bk = { 0, 0, 0, 0, 0, 0, 0, 0 };
                if (ok)
                    bk = *(const bf16x8*)(inP + ((size_t)(b * ncg + cgbase + cc * 4 + l4) * 9216
                                                 + gy * 96 + gx) * 8);
                acc = __builtin_amdgcn_mfma_f32_16x16x32_bf16(a, bk, acc, 0, 0, 0);
            }
        }
    }

    if (l4 == 0) {
        int px = p0 + l15;
        float aI = acc[0] + bias[0];
        float aF = acc[1] + bias[1];
        float aO = acc[2] + bias[2];
        float aG = acc[3] + bias[3];
        const float* hp = hprev + b * PIX;
#pragma unroll
        for (int ky = 0; ky < 3; ++ky) {
            int gy = y + ky - 1;
            if ((unsigned)gy >= 96u) continue;
#pragma unroll
            for (int kx = 0; kx < 3; ++kx) {
                int gx = x + kx - 1;
                if ((unsigned)gx >= 96u) continue;
                int tap = ky * 3 + kx;
                float hv = hp[gy * 96 + gx];
                aI = fmaf(w2[(0 * 65 + 64) * 9 + tap], hv, aI);
                aF = fmaf(w2[(1 * 65 + 64) * 9 + tap], hv, aF);
                aO = fmaf(w2[(2 * 65 + 64) * 9 + tap], hv, aO);
                aG = fmaf(w2[(3 * 65 + 64) * 9 + tap], hv, aG);
            }
        }
        int idx = b * PIX + px;
        float cn = sigmf_(aF) * cprev[idx] + sigmf_(aI) * tanhf_(aG);
        cout[idx] = cn;
        float h = sigmf_(aO) * tanhf_(cn);

        float a2 = tb[0];
#pragma unroll
        for (int c2 = 0; c2 < TIN; ++c2)
            a2 = fmaf(tw[c2], yprev[(size_t)(b * TIN + c2) * PIX + px], a2);
        a2 = fmaf(tw[TIN], h, a2);
        float o = fmaxf(a2, 0.0f);
        outp[(size_t)b * TOUT * PIX + px] = o;
#pragma unroll
        for (int c2 = 0; c2 < TIN - 1; ++c2)
            ynext[(size_t)(b * TIN + c2) * PIX + px] = yprev[(size_t)(b * TIN + c2 + 1) * PIX + px];
        ynext[(size_t)(b * TIN + 9) * PIX + px] = h;
        hcarry[idx] = o;
    }
}

// ---------------------------------------------------------------------------
// Steady-state encoder dispatch: [0,384) enc2[k] cell<4>;
// [384,768) enc1[k+1] cell<2,XCONV>; [768,1488) attnE[k+2].
// ---------------------------------------------------------------------------
__global__ void __launch_bounds__(256, 2)
mk_enc(const unsigned short* __restrict__ i2in, const unsigned short* __restrict__ wpe2,
       const float* __restrict__ b2, float* c2, unsigned short* __restrict__ i2n_hi,
       const float* __restrict__ zeropg,
       const unsigned short* __restrict__ i1in, const unsigned short* __restrict__ wpe1,
       const float* __restrict__ b1, float* c1,
       unsigned short* __restrict__ i1out, unsigned short* __restrict__ i2n_lo,
       const float* __restrict__ xim, const unsigned short* __restrict__ wxP,
       const unsigned short* __restrict__ xsp, const unsigned short* __restrict__ wiP,
       const float* __restrict__ h0, const float* __restrict__ c0,
       const float* __restrict__ wh, const float* __restrict__ bh,
       const float* __restrict__ bi, unsigned short* __restrict__ eP)
{
    __shared__ __align__(16) char smem[40960];
    if (blockIdx.x < 384)
        cell64_body<4, false>(smem, blockIdx.x, i2in, wpe2, b2, c2, c2, zeropg,
                              i2n_hi, 64, 16, nullptr, 0, 0, nullptr, nullptr);
    else if (blockIdx.x < 768)
        cell64_body<2, true>(smem, blockIdx.x - 384, i1in, wpe1, b1, c1, c1, zeropg,
                             i1out, 0, 8, i2n_lo, 0, 16, xim, wxP);
    else
        attnE_body(smem, blockIdx.x - 768, xsp, wiP, h0, c0, wh, bh, bi, eP);
}

// prologue dispatch: enc1[0] || attnE[1]
__global__ void __launch_bounds__(256, 2)
mk_cell_attnE(const unsigned short* __restrict__ inP, const unsigned short* __restrict__ wP,
              const float* __restrict__ bias, const float* cprev, float* cout,
              const float* __restrict__ zeropg,
              unsigned short* __restrict__ d1, int d1_coff, int d1_ncg,
              unsigned short* __restrict__ d2, int d2_coff, int d2_ncg,
              const float* __restrict__ xim, const unsigned short* __restrict__ wxP,
              const unsigned short* __restrict__ xsp, const unsigned short* __restrict__ wiP,
              const float* __restrict__ h0, const float* __restrict__ c0,
              const float* __restrict__ wh, const float* __restrict__ bh,
              const float* __restrict__ bi, unsigned short* __restrict__ eP)
{
    __shared__ __align__(16) char smem[40960];
    if (blockIdx.x < 384)
        cell64_body<2, true>(smem, blockIdx.x, inP, wP, bias, cprev, cout, zeropg,
                             d1, d1_coff, d1_ncg, d2, d2_coff, d2_ncg, xim, wxP);
    else
        attnE_body(smem, blockIdx.x - 384, xsp, wiP, h0, c0, wh, bh, bi, eP);
}

// ---------------------------------------------------------------------------
// Merged scale_pack + small_cell5 (inline-scaled).
// ---------------------------------------------------------------------------
__global__ void __launch_bounds__(256)
mk_scale_small5(const float* __restrict__ xs_cur, float* __restrict__ xs_nxt,
                unsigned short* __restrict__ xsp,
                const float* __restrict__ alpha, const unsigned* __restrict__ msl,
                int ts,
                const float* __restrict__ h0in, const float* cprev,
                const float* __restrict__ w, const float* __restrict__ bias,
                float* __restrict__ h0out, float* cout)
{
    __shared__ float z[4][64];
    const int bid = blockIdx.x;
    const float mval = funmap_(msl[0]);
    if (bid < 720) {
        int idx = bid * 256 + threadIdx.x;
        int p = idx % PIX;
        int q = idx / PIX;
        int d = q % ND, bb = q / ND;
        float wgt = __expf(alpha[idx] - mval);
        unsigned short tmp[16];
#pragma unroll
        for (int t = 0; t < TIN; ++t) {
            size_t xi = ((size_t)(bb * TIN + t) * ND + d) * PIX + p;
            float v = xs_cur[xi] * wgt;
            xs_nxt[xi] = v;
            tmp[t] = f2bf(v);
        }
#pragma unroll
        for (int t = TIN; t < 16; ++t) tmp[t] = 0;
        uint4* dst = (uint4*)(xsp + (size_t)idx * 16);
        dst[0] = *(uint4*)&tmp[0];
        dst[1] = *(uint4*)&tmp[8];
    } else {
        int bid2 = bid - 720;
        int bx = bid2 % 144, bb = bid2 / 144;
        const int pxl = threadIdx.x & 63, gate = threadIdx.x >> 6;
        const int p = bx * 64 + pxl;
        const int y = p / 96, x = p - y * 96;
        float acc = bias[gate];
#pragma unroll
        for (int cin = 0; cin < 6; ++cin) {
            const float* wp = w + (gate * 6 + cin) * 9;
#pragma unroll
            for (int ky = 0; ky < 3; ++ky) {
                int gy = y + ky - 1;
                if ((unsigned)gy >= 96u) continue;
#pragma unroll
                for (int kx = 0; kx < 3; ++kx) {
                    int gx = x + kx - 1;
                    if ((unsigned)gx >= 96u) continue;
                    int np = gy * 96 + gx;
                    float v;
                    if (cin < 5) {
                        float raw = xs_cur[((size_t)(bb * TIN + ts) * ND + cin) * PIX + np];
                        v = raw * __expf(alpha[(size_t)(bb * ND + cin) * PIX + np] - mval);
                    } else {
                        v = h0in[bb * PIX + np];
                    }
                    acc = fmaf(wp[ky * 3 + kx], v, acc);
                }
            }
        }
        z[gate][pxl] = acc;
        __syncthreads();
        if (threadIdx.x < 64) {
            int pp = bx * 64 + threadIdx.x;
            int idx = bb * PIX + pp;
            float cn = sigmf_(z[1][threadIdx.x]) * cprev[idx]
                     + sigmf_(z[0][threadIdx.x]) * tanhf_(z[3][threadIdx.x]);
            cout[idx] = cn;
            h0out[idx] = sigmf_(z[2][threadIdx.x]) * tanhf_(cn);
        }
    }
}

// ---------------------------------------------------------------------------
// Merged decoder dispatch: [0,384) dec1 cell<4>; [384,768) dec0 cell<2>;
// [768,1344) dec2+tcnn.
// ---------------------------------------------------------------------------
template <bool HAS0, bool HAS2>
__global__ void __launch_bounds__(256, 2)
mk_dec(const unsigned short* __restrict__ d1in, const unsigned short* __restrict__ wpd1,
       const float* __restrict__ b1, float* c1, unsigned short* __restrict__ d1out,
       const float* __restrict__ zeropg,
       const unsigned short* __restrict__ d0in, const unsigned short* __restrict__ wpd0,
       const float* __restrict__ b0, float* c2, unsigned short* __restrict__ d0out,
       unsigned short* __restrict__ d1next,
       const unsigned short* __restrict__ d2in,
       const float* __restrict__ hprev, float* c0,
       const unsigned short* __restrict__ wd2m, const float* __restrict__ w2,
       const float* __restrict__ b2,
       const float* __restrict__ tw, const float* __restrict__ tb,
       const float* __restrict__ yprev, float* __restrict__ ynext,
       float* __restrict__ hcarry, float* __restrict__ outp)
{
    __shared__ __align__(16) char smem[40960];
    if (blockIdx.x < 384) {
        cell64_body<4, false>(smem, blockIdx.x, d1in, wpd1, b1, c1, c1, zeropg,
                              d1out, 64, 16, nullptr, 0, 0, nullptr, nullptr);
    } else if (blockIdx.x < 768) {
        if (HAS0)
            cell64_body<2, false>(smem, blockIdx.x - 384, d0in, wpd0, b0, c2, c2, zeropg,
                                  d0out, 0, 8, d1next, 0, 16, nullptr, nullptr);
    } else {
        if (HAS2)
            dec2_body(blockIdx.x - 768, d2in, 16, 8, hprev, c0, wd2m, w2, b2,
                      tw, tb, yprev, ynext, hcarry, outp, c0);
    }
}

// standalone wrappers
template <int NCH, bool XCONV>
__global__ void __launch_bounds__(256, 2)
cell_k(const unsigned short* __restrict__ inP, const unsigned short* __restrict__ wP,
       const float* __restrict__ bias, const float* cprev, float* cout,
       const float* __restrict__ zeropg,
       unsigned short* __restrict__ d1, int d1_coff, int d1_ncg,
       unsigned short* __restrict__ d2, int d2_coff, int d2_ncg,
       const float* __restrict__ xim, const unsigned short* __restrict__ wxP)
{
    __shared__ __align__(16) char smem[40960];
    cell64_body<NCH, XCONV>(smem, blockIdx.x, inP, wP, bias, cprev, cout, zeropg,
                            d1, d1_coff, d1_ncg, d2, d2_coff, d2_ncg, xim, wxP);
}

__global__ void __launch_bounds__(256)
dec2_k(const unsigned short* __restrict__ d2in, const float* __restrict__ hprev,
       float* c0, const unsigned short* __restrict__ wd2m, const float* __restrict__ w2,
       const float* __restrict__ b2, const float* __restrict__ tw, const float* __restrict__ tb,
       const float* __restrict__ yprev, float* __restrict__ ynext,
       float* __restrict__ hcarry, float* __restrict__ outp)
{
    dec2_body(blockIdx.x, d2in, 16, 8, hprev, c0, wd2m, w2, b2,
              tw, tb, yprev, ynext, hcarry, outp, c0);
}

__global__ void __launch_bounds__(256)
attn_e_k(const unsigned short* __restrict__ xsp, const unsigned short* __restrict__ wiP,
         const float* __restrict__ h0, const float* __restrict__ c0,
         const float* __restrict__ wh, const float* __restrict__ bh,
         const float* __restrict__ bi, unsigned short* __restrict__ eP)
{
    __shared__ __align__(16) char smem[33792];
    attnE_body(smem, blockIdx.x, xsp, wiP, h0, c0, wh, bh, bi, eP);
}

__global__ void __launch_bounds__(256)
alpha_k(const unsigned short* __restrict__ eP, const float* __restrict__ wvv,
        const float* __restrict__ bv, float* __restrict__ alpha, unsigned* __restrict__ msl)
{
    __shared__ __align__(16) char smem[1024];
    alpha_body(smem, blockIdx.x, eP, wvv, bv, alpha, msl);
}

// ---------------------------------------------------------------------------
// One-shot prep mega-kernel (gate-interleaved weight packing + xsp + y slice).
// ---------------------------------------------------------------------------
__global__ void __launch_bounds__(256)
prep_kernel(const float* __restrict__ enc_w1, const float* __restrict__ enc_w2,
            const float* __restrict__ dec_w0, const float* __restrict__ dec_w1,
            const float* __restrict__ dec_w2, const float* __restrict__ attn_wi,
            const float* __restrict__ x,
            unsigned short* __restrict__ wpe1, unsigned short* __restrict__ wpe2,
            unsigned short* __restrict__ wpd0, unsigned short* __restrict__ wpd1,
            unsigned short* __restrict__ wd2m, unsigned short* __restrict__ wiP,
            unsigned short* __restrict__ wxP,
            unsigned short* __restrict__ xsp, float* __restrict__ yp)
{
    int gid = blockIdx.x;
    auto wpack = [&](const float* w, unsigned short* wp, int WCIN, int NCH,
                     int coff, int climit, int base) {
        int idx = (gid - base) * 256 + threadIdx.x;
        if (idx >= 9 * NCH * 256 * 32) return;
        int k = idx & 31;
        int ocp = (idx >> 5) & 255;
        int rest = idx >> 13;
        int cc = rest % NCH, tap = rest / NCH;
        int hc = ocp >> 2, gate = ocp & 3;
        int c = cc * 32 + k;
        float v = 0.0f;
        if (c < climit) v = w[((gate * 64 + hc) * WCIN + (c + coff)) * 9 + tap];
        wp[idx] = f2bf(v);
    };
    if (gid < 576) { wpack(enc_w1, wpe1, 65, 2, 1, 64, 0); return; }
    if (gid < 1728) { wpack(enc_w2, wpe2, 128, 4, 0, 128, 576); return; }
    if (gid < 2304) { wpack(dec_w0, wpd0, 65, 2, 1, 64, 1728); return; }
    if (gid < 3456) { wpack(dec_w1, wpd1, 128, 4, 0, 128, 2304); return; }
    if (gid < 3492) {
        int idx = (gid - 3456) * 256 + threadIdx.x;
        if (idx < 9 * 2 * 16 * 32) {
            int k = idx & 31;
            int oc = (idx >> 5) & 15;
            int cc = (idx >> 9) & 1;
            int tap = idx >> 10;
            float v = 0.0f;
            if (oc < 4) v = dec_w2[(oc * 65 + cc * 32 + k) * 9 + tap];
            wd2m[idx] = f2bf(v);
        }
        return;
    }
    if (gid < 3512) {
        int idx = (gid - 3492) * 256 + threadIdx.x;
        if (idx < 5120) {
            int kl = idx & 31, oc = (idx >> 5) & 31, j = idx >> 10;
            int tappos = kl >> 4, ch = kl & 15;
            int tap = 2 * j + tappos;
            float v = 0.0f;
            if (tap < 9 && ch < 10) v = attn_wi[(oc * TIN + ch) * 9 + tap];
            wiP[idx] = f2bf(v);
        }
        return;
    }
    if (gid < 3544) {
        int idx = (gid - 3512) * 256 + threadIdx.x;
        if (idx < 8192) {
            int s = idx & 31;
            int ocp = idx >> 5;
            int hc = ocp >> 2, gate = ocp & 3;
            float v = 0.0f;
            if (s < 9) v = enc_w1[((gate * 64 + hc) * 65 + 0) * 9 + s];
            wxP[idx] = f2bf(v);
        }
        return;
    }
    if (gid < 4264) {
        int idx = (gid - 3544) * 256 + threadIdx.x;
        int p = idx % PIX;
        int q = idx / PIX;
        int d = q % ND, bb = q / ND;
        unsigned short tmp[16];
#pragma unroll
        for (int t = 0; t < TIN; ++t)
            tmp[t] = f2bf(x[((size_t)(bb * TIN + t) * ND + d) * PIX + p]);
#pragma unroll
        for (int t = TIN; t < 16; ++t) tmp[t] = 0;
        uint4* dst = (uint4*)(xsp + (size_t)idx * 16);
        dst[0] = *(uint4*)&tmp[0];
        dst[1] = *(uint4*)&tmp[8];
        return;
    }
    {
        int idx = (gid - 4264) * 256 + threadIdx.x;
        int p = idx % PIX;
        int q = idx / PIX;
        yp[idx] = x[(size_t)(q * ND + 0) * PIX + p];
    }
}

// ---------------------------------------------------------------------------
extern "C" void kernel_launch(void* const* d_in, const int* in_sizes, int n_in,
                              void* d_out, int out_size, void* d_ws, size_t ws_size,
                              hipStream_t stream)
{
    const float* x       = (const float*)d_in[0];
    const float* enc_w0  = (const float*)d_in[1];
    const float* enc_b0  = (const float*)d_in[2];
    const float* enc_w1  = (const float*)d_in[3];
    const float* enc_b1  = (const float*)d_in[4];
    const float* enc_w2  = (const float*)d_in[5];
    const float* enc_b2  = (const float*)d_in[6];
    const float* dec_w0  = (const float*)d_in[7];
    const float* dec_b0  = (const float*)d_in[8];
    const float* dec_w1  = (const float*)d_in[9];
    const float* dec_b1  = (const float*)d_in[10];
    const float* dec_w2  = (const float*)d_in[11];
    const float* dec_b2  = (const float*)d_in[12];
    const float* attn_wi = (const float*)d_in[13];
    const float* attn_bi = (const float*)d_in[14];
    const float* attn_wh = (const float*)d_in[15];
    const float* attn_bh = (const float*)d_in[16];
    const float* attn_wv = (const float*)d_in[17];
    const float* attn_bv = (const float*)d_in[18];
    const float* tcnn_w  = (const float*)d_in[19];
    const float* tcnn_b  = (const float*)d_in[20];
    float* out = (float*)d_out;

    char* cur = (char*)d_ws;
    auto alloc = [&](size_t bytes) { char* p = cur; cur += (bytes + 255) & ~(size_t)255; return p; };
    float* xsA  = (float*)alloc((size_t)NB * TIN * ND * PIX * 4);
    float* xsB  = (float*)alloc((size_t)NB * TIN * ND * PIX * 4);
    float* alp  = (float*)alloc((size_t)NB * ND * PIX * 4);
    float* ypa  = (float*)alloc((size_t)NB * TIN * PIX * 4);
    float* ypb  = (float*)alloc((size_t)NB * TIN * PIX * 4);
    unsigned short* wpe1 = (unsigned short*)alloc((size_t)9 * 2 * 256 * 32 * 2);
    unsigned short* wpe2 = (unsigned short*)alloc((size_t)9 * 4 * 256 * 32 * 2);
    unsigned short* wpd0 = (unsigned short*)alloc((size_t)9 * 2 * 256 * 32 * 2);
    unsigned short* wpd1 = (unsigned short*)alloc((size_t)9 * 4 * 256 * 32 * 2);
    unsigned short* wd2m = (unsigned short*)alloc((size_t)9 * 2 * 16 * 32 * 2);
    unsigned short* wiP  = (unsigned short*)alloc(5120 * 2);
    unsigned short* wxP  = (unsigned short*)alloc(8192 * 2);
    unsigned short* xsp  = (unsigned short*)alloc((size_t)NB * ND * PIX * 16 * 2);
    unsigned short* eP   = (unsigned short*)alloc((size_t)NB * ND * PIX * 32 * 2);
    // ---- contiguous zero-init region ----
    char* zbeg = cur;
    float* h0a  = (float*)alloc(NB * PIX * 4);
    float* h0b  = (float*)alloc(NB * PIX * 4);
    float* c0   = (float*)alloc(NB * PIX * 4);
    float* c1   = (float*)alloc((size_t)NB * HID * PIX * 4);
    float* c2   = (float*)alloc((size_t)NB * HID * PIX * 4);
    const size_t IN1_B = (size_t)NB * 8 * PIX * 8 * 2;    // 64ch packed
    const size_t IN2_B = (size_t)NB * 16 * PIX * 8 * 2;   // 128ch packed
    unsigned short* In1a = (unsigned short*)alloc(IN1_B);
    unsigned short* In1b = (unsigned short*)alloc(IN1_B);
    unsigned short* In2a = (unsigned short*)alloc(IN2_B);
    unsigned short* In2b = (unsigned short*)alloc(IN2_B);
    unsigned* mslot = (unsigned*)alloc(256);
    float* zeropg = (float*)alloc(256);
    char* zend = cur;

    hipMemcpyAsync(xsA, x, (size_t)NB * TIN * ND * PIX * 4, hipMemcpyDeviceToDevice, stream);
    hipMemsetAsync(zbeg, 0, (size_t)(zend - zbeg), stream);
    prep_kernel<<<dim3(5704), 256, 0, stream>>>(enc_w1, enc_w2, dec_w0, dec_w1, dec_w2,
                                                attn_wi, x, wpe1, wpe2, wpd0, wpd1,
                                                wd2m, wiP, wxP, xsp, ypa);

    dim3 blk(64, 4);
    float *h0 = h0a, *h0n = h0b;
    float *xc = xsA, *xn = xsB;
    unsigned short* In1[2] = { In1a, In1b };
    unsigned short* In2[2] = { In2a, In2b };

    // ---------------- encoder prologue ----------------
    // attnE[0], alpha[0], C[0] -> h0[0]
    attn_e_k<<<dim3(720), blk, 0, stream>>>(xsp, wiP, h0, c0, attn_wh, attn_bh, attn_bi, eP);
    alpha_k<<<dim3(720), blk, 0, stream>>>(eP, attn_wv, attn_bv, alp, mslot + 0);
    mk_scale_small5<<<dim3(1296), 256, 0, stream>>>(xc, xn, xsp, alp, mslot + 0, 0,
                                                    h0, c0, enc_w0, enc_b0, h0n, c0);
    { float* tmp = h0; h0 = h0n; h0n = tmp; }   // h0 = h0[0]
    { float* tmp = xc; xc = xn; xn = tmp; }
    // B': enc1[0] || attnE[1]   (enc1[0]: reads In1[0](zeros)+h0[0]; d1->In1[1]; d2->In2[0] lo)
    mk_cell_attnE<<<dim3(1104), blk, 0, stream>>>(In1[0], wpe1, enc_b1, c1, c1, zeropg,
                                                  In1[1], 0, 8, In2[0], 0, 16,
                                                  h0, wxP,
                                                  xsp, wiP, h0, c0,
                                                  attn_wh, attn_bh, attn_bi, eP);
    // alpha[1], C[1] -> h0[1]
    alpha_k<<<dim3(720), blk, 0, stream>>>(eP, attn_wv, attn_bv, alp, mslot + 1);
    mk_scale_small5<<<dim3(1296), 256, 0, stream>>>(xc, xn, xsp, alp, mslot + 1, 1,
                                                    h0, c0, enc_w0, enc_b0, h0n, c0);
    { float* tmp = h0; h0 = h0n; h0n = tmp; }   // h0 = h0[1]
    { float* tmp = xc; xc = xn; xn = tmp; }

    // ---------------- encoder steady state: k = 0..7 ----------------
    // B_k: enc2[k] || enc1[k+1] || attnE[k+2]; then alpha[k+2], C[k+2].
    for (int k = 0; k <= 7; ++k) {
        unsigned short* i2k = In2[k & 1];
        unsigned short* i2n = In2[(k + 1) & 1];
        unsigned short* i1in  = In1[(k + 1) & 1];
        unsigned short* i1out = In1[k & 1];
        mk_enc<<<dim3(1488), blk, 0, stream>>>(
            i2k, wpe2, enc_b2, c2, i2n, zeropg,
            i1in, wpe1, enc_b1, c1, i1out, i2n,
            h0, wxP,
            xsp, wiP, h0, c0, attn_wh, attn_bh, attn_bi, eP);
        alpha_k<<<dim3(720), blk, 0, stream>>>(eP, attn_wv, attn_bv, alp, mslot + k + 2);
        mk_scale_small5<<<dim3(1296), 256, 0, stream>>>(xc, xn, xsp, alp, mslot + k + 2,
                                                        k + 2, h0, c0, enc_w0, enc_b0,
                                                        h0n, c0);
        { float* tmp = h0; h0 = h0n; h0n = tmp; }   // h0 = h0[k+2]
        { float* tmp = xc; xc = xn; xn = tmp; }
    }

    // ---------------- encoder tail ----------------
    // B_8: enc2[8] (reads In2[0]; d1 -> In2[1] hi)
    cell_k<4, false><<<dim3(384), blk, 0, stream>>>(In2[0], wpe2, enc_b2, c2, c2, zeropg,
                                                    In2[1], 64, 16, nullptr, 0, 0,
                                                    nullptr, nullptr);
    // A9: enc1[9] (reads In1[1] + h0[9]; d1 -> In2a+64 (h1-final), d2 -> In2[1] lo)
    cell_k<2, true><<<dim3(384), blk, 0, stream>>>(In1[1], wpe1, enc_b1, c1, c1, zeropg,
                                                   In2a, 64, 16, In2[1], 0, 16,
                                                   h0, wxP);
    // B_9: enc2[9] (reads In2[1]; d1 -> In1a lo = h2-final for dec0)
    cell_k<4, false><<<dim3(384), blk, 0, stream>>>(In2[1], wpe2, enc_b2, c2, c2, zeropg,
                                                    In1a, 0, 8, nullptr, 0, 0,
                                                    nullptr, nullptr);

    // ---------------- decoder (pipelined: dec1[t] || dec0[t+1] || dec2[t-1]) --
    float *hc = h0, *hcn = h0n;
    // D0: dec0[0]
    cell_k<2, false><<<dim3(384), blk, 0, stream>>>(In1a, wpd0, dec_b0, c2, c2, zeropg,
                                                    In1b, 0, 8, In2a, 0, 16,
                                                    nullptr, nullptr);
    // D1: dec1[0] || dec0[1]
    mk_dec<true, false><<<dim3(768), blk, 0, stream>>>(
        In2a, wpd1, dec_b1, c1, In2b, zeropg,
        In1b, wpd0, dec_b0, c2, In1a, In2b,
        nullptr, nullptr, nullptr, nullptr, nullptr, nullptr, nullptr, nullptr,
        nullptr, nullptr, nullptr, nullptr);
    // D2: dec1[1] || dec0[2] || dec2[0]
    mk_dec<true, true><<<dim3(1344), blk, 0, stream>>>(
        In2b, wpd1, dec_b1, c1, In2a, zeropg,
        In1a, wpd0, dec_b0, c2, In1b, In2a,
        In2b, hc, c0, wd2m, dec_w2, dec_b2, tcnn_w, tcnn_b,
        ypa, ypb, hcn, out + 0 * PIX);
    // D3: dec1[2] || dec0[3] || dec2[1]
    mk_dec<true, true><<<dim3(1344), blk, 0, stream>>>(
        In2a, wpd1, dec_b1, c1, In2b, zeropg,
        In1b, wpd0, dec_b0, c2, In1a, In2b,
        In2a, hcn, c0, wd2m, dec_w2, dec_b2, tcnn_w, tcnn_b,
        ypb, ypa, hc, out + 1 * PIX);
    // D4: dec1[3] || dec0[4] || dec2[2]
    mk_dec<true, true><<<dim3(1344), blk, 0, stream>>>(
        In2b, wpd1, dec_b1, c1, In2a, zeropg,
        In1a, wpd0, dec_b0, c2, In1b, In2a,
        In2b, hc, c0, wd2m, dec_w2, dec_b2, tcnn_w, tcnn_b,
        ypa, ypb, hcn, out + 2 * PIX);
    // D5: dec1[4] || dec2[3]
    mk_dec<false, true><<<dim3(1344), blk, 0, stream>>>(
        In2a, wpd1, dec_b1, c1, In2b, zeropg,
        nullptr, nullptr, nullptr, nullptr, nullptr, nullptr,
        In2a, hcn, c0, wd2m, dec_w2, dec_b2, tcnn_w, tcnn_b,
        ypb, ypa, hc, out + 3 * PIX);
    // D6: dec2[4]
    dec2_k<<<dim3(576), blk, 0, stream>>>(In2b, hc, c0, wd2m, dec_w2, dec_b2,
                                          tcnn_w, tcnn_b, ypa, ypb, hcn, out + 4 * PIX);
}

// Round 18
// 1265.770 us; speedup vs baseline: 1.0372x; 1.0372x over previous
//
#include <hip/hip_runtime.h>

// WeatherModel: ConvLSTM encoder-decoder with attention.
// All heavy convs on bf16 MFMA implicit GEMM; independent ops co-scheduled
// in merged dispatches (encoder: cell+attn, scale+small5; decoder: dec1||dec0||dec2).
// B=4, T_IN=10, T_OUT=5, D=5, M=N=96, H1=64, ATTN=32, SEL=0.
// (Round-18: revert to measured-best round-14 configuration, 1269.8 us.)

#define PIX  9216
#define NB   4
#define TIN  10
#define TOUT 5
#define ND   5
#define HID  64

typedef __attribute__((ext_vector_type(8))) short bf16x8;
typedef __attribute__((ext_vector_type(4))) float f32x4;

__device__ __forceinline__ float sigmf_(float x) { return 1.0f / (1.0f + __expf(-x)); }
__device__ __forceinline__ float tanhf_(float x) { return 1.0f - 2.0f / (__expf(2.0f * x) + 1.0f); }
__device__ __forceinline__ unsigned short f2bf(float f) {
    unsigned u = __float_as_uint(f);
    unsigned r = u + 0x7FFFu + ((u >> 16) & 1u);
    return (unsigned short)(r >> 16);
}
__device__ __forceinline__ float bf2f(unsigned short u) {
    return __uint_as_float(((unsigned)u) << 16);
}
__device__ __forceinline__ unsigned fmap_(float f) {
    unsigned u = __float_as_uint(f);
    return (u & 0x80000000u) ? ~u : (u | 0x80000000u);
}
__device__ __forceinline__ float funmap_(unsigned v) {
    return __uint_as_float((v & 0x80000000u) ? (v ^ 0x80000000u) : ~v);
}
__device__ __forceinline__ void gload_lds16(const void* g, void* l) {
    __builtin_amdgcn_global_load_lds(
        (const __attribute__((address_space(1))) void*)g,
        (__attribute__((address_space(3))) void*)l, 16, 0, 0);
}

// ---------------------------------------------------------------------------
// cell64 body: XCD swizzle + setprio + global_load_lds staging + af RING-3.
// block (64,4); bid in [0,384); LDS 2 x 20480 at smem.
// ---------------------------------------------------------------------------
template <int NCH>
__device__ __forceinline__ void
cell64_body(char* smem, int bid,
            const unsigned short* __restrict__ inP,
            const unsigned short* __restrict__ wP,
            const float* __restrict__ bias,
            const float* cprev, float* cout,
            const float* __restrict__ zeropg,
            unsigned short* __restrict__ d1, int d1_coff, int d1_ncg,
            unsigned short* __restrict__ d2, int d2_coff, int d2_ncg)
{
    const int lane = threadIdx.x;
    const int wv   = threadIdx.y;
    const int tid  = wv * 64 + lane;
    const int rid = (bid & 7) * 48 + (bid >> 3);
    const int y = rid % 96, b = rid / 96;
    const int l15 = lane & 15, l4 = lane >> 4;
    const int NCG = NCH * 4;

    const int scg  = tid & 3;
    const int spr0 = tid >> 2;

    auto stage = [&](char* buf, int cc) {
#pragma unroll
        for (int i = 0; i < 5; ++i) {
            int pr = spr0 + i * 64;
            int r = pr / 98;
            int p = pr - r * 98;
            int gy = y - 1 + r, gx = p - 1;
            const void* g = (const void*)zeropg;
            if (pr < 294 && (unsigned)gy < 96u && (unsigned)gx < 96u) {
                int cg = scg ^ ((p >> 1) & 3);
                g = (const void*)(inP + (((size_t)(b * NCG + cc * 4 + cg) * 9216
                                          + gy * 96 + gx) << 3));
            }
            gload_lds16(g, buf + i * 4096 + wv * 1024);
        }
    };

    f32x4 acc[4][6] = {};
    bf16x8 af[3][4];                               // tap ring, prefetch dist 2

#pragma unroll
    for (int t0 = 0; t0 < 2; ++t0)                 // preload T=0,1 (cc=0)
#pragma unroll
        for (int g = 0; g < 4; ++g)
            af[t0][g] = *(const bf16x8*)(wP
                + ((size_t)(t0 * NCH + 0) * 256 + g * 64 + wv * 16 + l15) * 32 + l4 * 8);

    stage(smem, 0);
    __syncthreads();
#pragma unroll
    for (int cc = 0; cc < NCH; ++cc) {
        if (cc + 1 < NCH) stage(smem + ((cc + 1) & 1) * 20480, cc + 1);
        const char* buf = smem + (cc & 1) * 20480;
#pragma unroll
        for (int tap = 0; tap < 9; ++tap) {
            const int T = cc * 9 + tap;
            const int Tp = T + 2;
            if (Tp < NCH * 9) {                    // prefetch weights 2 taps ahead
                const int cc2 = Tp / 9, tap2 = Tp % 9;
#pragma unroll
                for (int g = 0; g < 4; ++g)
                    af[Tp % 3][g] = *(const bf16x8*)(wP
                        + ((size_t)(tap2 * NCH + cc2) * 256 + g * 64 + wv * 16 + l15) * 32 + l4 * 8);
            }
            const int ky = tap / 3, kx = tap % 3;
            bf16x8 bk[6];
#pragma unroll
            for (int k = 0; k < 6; ++k) {
                int p = k * 16 + kx + l15;
                int slot = l4 ^ ((p >> 1) & 3);
                bk[k] = *(const bf16x8*)(buf + (ky * 98 + p) * 64 + slot * 16);
            }
            __builtin_amdgcn_s_setprio(1);
#pragma unroll
            for (int g = 0; g < 4; ++g)
#pragma unroll
                for (int k = 0; k < 6; ++k)
                    acc[g][k] = __builtin_amdgcn_mfma_f32_16x16x32_bf16(
                        af[T % 3][g], bk[k], acc[g][k], 0, 0, 0);
            __builtin_amdgcn_s_setprio(0);
        }
        if (cc + 1 < NCH) __syncthreads();
    }

#pragma unroll
    for (int r = 0; r < 4; ++r) {
        int hc = wv * 16 + l4 * 4 + r;
        float bi = bias[hc], bff = bias[64 + hc];
        float bo = bias[128 + hc], bg = bias[192 + hc];
#pragma unroll
        for (int k = 0; k < 6; ++k) {
            int px = k * 16 + l15;
            int gpix = y * 96 + px;
            float ii = sigmf_(acc[0][k][r] + bi);
            float ff = sigmf_(acc[1][k][r] + bff);
            float oo = sigmf_(acc[2][k][r] + bo);
            float gg = tanhf_(acc[3][k][r] + bg);
            int cidx = (b * HID + hc) * 9216 + gpix;
            float cn = ff * cprev[cidx] + ii * gg;
            cout[cidx] = cn;
            unsigned short hb = f2bf(oo * tanhf_(cn));
            int ch1 = d1_coff + hc;
            d1[((size_t)(b * d1_ncg + (ch1 >> 3)) * 9216 + gpix) * 8 + (ch1 & 7)] = hb;
            if (d2) {
                int ch2 = d2_coff + hc;
                d2[((size_t)(b * d2_ncg + (ch2 >> 3)) * 9216 + gpix) * 8 + (ch2 & 7)] = hb;
            }
        }
    }
}

// ---------------------------------------------------------------------------
// attn_e body (hidE fused); block (64,4); aid in [0,720).
// ---------------------------------------------------------------------------
__device__ __forceinline__ void
attnE_body(char* smem, int aid,
           const unsigned short* __restrict__ xsp, const unsigned short* __restrict__ wiP,
           const float* __restrict__ h0, const float* __restrict__ c0,
           const float* __restrict__ wh, const float* __restrict__ bh,
           const float* __restrict__ bi, unsigned short* __restrict__ eP)
{
    float* heS = (float*)smem;
    const int lane = threadIdx.x, wvid = threadIdx.y;
    const int tile = aid % 36, k = (aid / 36) % 5, bb = aid / 180;
    const int l15 = lane & 15, l4 = lane >> 4;
    const int tid = wvid * 64 + lane;

    {
        int p = tile * 256 + tid;
        int y = p / 96, x = p - y * 96;
        float hv9[9], cv9[9];
        const float* hp = h0 + bb * PIX;
        const float* cp = c0 + bb * PIX;
#pragma unroll
        for (int t9 = 0; t9 < 9; ++t9) {
            int gy = y + t9 / 3 - 1, gx = x + t9 % 3 - 1;
            bool ok = (unsigned)gy < 96u && (unsigned)gx < 96u;
            hv9[t9] = ok ? hp[gy * 96 + gx] : 0.0f;
            cv9[t9] = ok ? cp[gy * 96 + gx] : 0.0f;
        }
#pragma unroll
        for (int ch = 0; ch < 32; ++ch) {
            float a = bi[ch] + bh[ch];
#pragma unroll
            for (int t9 = 0; t9 < 9; ++t9) {
                a = fmaf(wh[(ch * 2 + 0) * 9 + t9], hv9[t9], a);
                a = fmaf(wh[(ch * 2 + 1) * 9 + t9], cv9[t9], a);
            }
            heS[tid * 33 + ch] = a;
        }
    }

    bf16x8 af[5][2];
#pragma unroll
    for (int j = 0; j < 5; ++j)
#pragma unroll
        for (int m = 0; m < 2; ++m)
            af[j][m] = *(const bf16x8*)(wiP + ((size_t)(j * 32 + m * 16 + l15)) * 32 + l4 * 8);

    const unsigned short* xb = xsp + (size_t)(bb * ND + k) * PIX * 16;
    const int p0 = tile * 256 + wvid * 64;

    f32x4 acc[4][2] = {};
#pragma unroll
    for (int nf = 0; nf < 4; ++nf) {
        int p = p0 + nf * 16 + l15;
        int y = p / 96, x = p - y * 96;
#pragma unroll
        for (int j = 0; j < 5; ++j) {
            int tp = 2 * j + (l4 >> 1);
            bf16x8 bk = { 0, 0, 0, 0, 0, 0, 0, 0 };
            if (tp < 9) {
                int gy = y + tp / 3 - 1, gx = x + tp % 3 - 1;
                if ((unsigned)gy < 96u && (unsigned)gx < 96u)
                    bk = *(const bf16x8*)(xb + ((size_t)(gy * 96 + gx)) * 16 + (l4 & 1) * 8);
            }
            acc[nf][0] = __builtin_amdgcn_mfma_f32_16x16x32_bf16(af[j][0], bk, acc[nf][0], 0, 0, 0);
            acc[nf][1] = __builtin_amdgcn_mfma_f32_16x16x32_bf16(af[j][1], bk, acc[nf][1], 0, 0, 0);
        }
    }

    __syncthreads();

#pragma unroll
    for (int nf = 0; nf < 4; ++nf) {
        int p = p0 + nf * 16 + l15;
        int pl = wvid * 64 + nf * 16 + l15;
        const float* hrow = &heS[pl * 33];
#pragma unroll
        for (int m = 0; m < 2; ++m) {
            ushort4 o;
            o.x = f2bf(tanhf_(acc[nf][m][0] + hrow[m * 16 + l4 * 4 + 0]));
            o.y = f2bf(tanhf_(acc[nf][m][1] + hrow[m * 16 + l4 * 4 + 1]));
            o.z = f2bf(tanhf_(acc[nf][m][2] + hrow[m * 16 + l4 * 4 + 2]));
            o.w = f2bf(tanhf_(acc[nf][m][3] + hrow[m * 16 + l4 * 4 + 3]));
            *(ushort4*)(eP + ((size_t)(bb * ND + k) * PIX + p) * 32 + m * 16 + l4 * 4) = o;
        }
    }
}

// ---------------------------------------------------------------------------
__device__ __forceinline__ void
alpha_body(char* smem, int aid,
           const unsigned short* __restrict__ eP, const float* __restrict__ wvv,
           const float* __restrict__ bv, float* __restrict__ alpha,
           unsigned* __restrict__ msl)
{
    const int tid = threadIdx.y * 64 + threadIdx.x;
    const int tile = aid % 36, k = (aid / 36) % 5, bb = aid / 180;
    int p = tile * 256 + tid;
    int y = p / 96, x = p - y * 96;
    const unsigned short* eb = eP + (size_t)(bb * ND + k) * PIX * 32;
    float acc = bv[0];
#pragma unroll
    for (int ky = 0; ky < 3; ++ky) {
        int gy = y + ky - 1;
        if ((unsigned)gy >= 96u) continue;
#pragma unroll
        for (int kx = 0; kx < 3; ++kx) {
            int gx = x + kx - 1;
            if ((unsigned)gx >= 96u) continue;
            int tap = ky * 3 + kx;
            const unsigned short* ee = eb + ((size_t)(gy * 96 + gx)) * 32;
#pragma unroll
            for (int cg = 0; cg < 4; ++cg) {
                bf16x8 ev = *(const bf16x8*)(ee + cg * 8);
#pragma unroll
                for (int jj = 0; jj < 8; ++jj)
                    acc = fmaf(wvv[(cg * 8 + jj) * 9 + tap], bf2f((unsigned short)ev[jj]), acc);
            }
        }
    }
    alpha[(size_t)(bb * ND + k) * PIX + p] = acc;

    float* s = (float*)smem;
    s[tid] = acc;
    __syncthreads();
    for (int st = 128; st > 0; st >>= 1) {
        if (tid < st) s[tid] = fmaxf(s[tid], s[tid + st]);
        __syncthreads();
    }
    if (tid == 0) atomicMax(msl, fmap_(s[0]));
}

// ---------------------------------------------------------------------------
// dec2+tcnn body; block (64,4); did in [0,576).
// ---------------------------------------------------------------------------
__device__ __forceinline__ void
dec2_body(int did,
          const unsigned short* __restrict__ inP, int ncg, int cgbase,
          const float* __restrict__ hprev, const float* cprev,
          const unsigned short* __restrict__ wm, const float* __restrict__ w2,
          const float* __restrict__ bias,
          const float* __restrict__ tw, const float* __restrict__ tb,
          const float* __restrict__ yprev,
          float* __restrict__ ynext, float* __restrict__ hcarry,
          float* __restrict__ outp, float* cout)
{
    const int wv = threadIdx.y, lane = threadIdx.x;
    const int l15 = lane & 15, l4 = lane >> 4;
    const int bx = did % 144, b = did / 144;
    const int p0 = (bx * 4 + wv) * 16;
    const int y = p0 / 96, xbase = p0 - y * 96;
    const int x = xbase + l15;

    f32x4 acc = {0.f, 0.f, 0.f, 0.f};
#pragma unroll
    for (int ky = 0; ky < 3; ++ky) {
        int gy = y + ky - 1;
        bool oky = (unsigned)gy < 96u;
#pragma unroll
        for (int kx = 0; kx < 3; ++kx) {
            const int tap = ky * 3 + kx;
            int gx = x + kx - 1;
            bool ok = oky && ((unsigned)gx < 96u);
#pragma unroll
            for (int cc = 0; cc < 2; ++cc) {
                bf16x8 a = *(const bf16x8*)(wm + ((size_t)(tap * 2 + cc) * 16 + l15) * 32 + l4 * 8);
                bf16x8 bk = { 0, 0, 0, 0, 0, 0, 0, 0 };
                if (ok)
                    bk = *(const bf16x8*)(inP + ((size_t)(b * ncg + cgbase + cc * 4 + l4) * 9216
                                                 + gy * 96 + gx) * 8);
                acc = __builtin_amdgcn_mfma_f32_16x16x32_bf16(a, bk, acc, 0, 0, 0);
            }
        }
    }

    if (l4 == 0) {
        int px = p0 + l15;
        float aI = acc[0] + bias[0];
        float aF = acc[1] + bias[1];
        float aO = acc[2] + bias[2];
        float aG = acc[3] + bias[3];
        const float* hp = hprev + b * PIX;
#pragma unroll
        for (int ky = 0; ky < 3; ++ky) {
            int gy = y + ky - 1;
            if ((unsigned)gy >= 96u) continue;
#pragma unroll
            for (int kx = 0; kx < 3; ++kx) {
                int gx = x + kx - 1;
                if ((unsigned)gx >= 96u) continue;
                int tap = ky * 3 + kx;
                float hv = hp[gy * 96 + gx];
                aI = fmaf(w2[(0 * 65 + 64) * 9 + tap], hv, aI);
                aF = fmaf(w2[(1 * 65 + 64) * 9 + tap], hv, aF);
                aO = fmaf(w2[(2 * 65 + 64) * 9 + tap], hv, aO);
                aG = fmaf(w2[(3 * 65 + 64) * 9 + tap], hv, aG);
            }
        }
        int idx = b * PIX + px;
        float cn = sigmf_(aF) * cprev[idx] + sigmf_(aI) * tanhf_(aG);
        cout[idx] = cn;
        float h = sigmf_(aO) * tanhf_(cn);

        float a2 = tb[0];
#pragma unroll
        for (int c2 = 0; c2 < TIN; ++c2)
            a2 = fmaf(tw[c2], yprev[(size_t)(b * TIN + c2) * PIX + px], a2);
        a2 = fmaf(tw[TIN], h, a2);
        float o = fmaxf(a2, 0.0f);
        outp[(size_t)b * TOUT * PIX + px] = o;
#pragma unroll
        for (int c2 = 0; c2 < TIN - 1; ++c2)
            ynext[(size_t)(b * TIN + c2) * PIX + px] = yprev[(size_t)(b * TIN + c2 + 1) * PIX + px];
        ynext[(size_t)(b * TIN + 9) * PIX + px] = h;
        hcarry[idx] = o;
    }
}

// ---------------------------------------------------------------------------
// Merged encoder dispatches: [0,384) cell64, [384,1104) attention.
// ---------------------------------------------------------------------------
template <int NCH, bool ATTN>
__global__ void __launch_bounds__(256, 2)
mk_cell_attnE(const unsigned short* __restrict__ inP, const unsigned short* __restrict__ wP,
              const float* __restrict__ bias, const float* cprev, float* cout,
              const float* __restrict__ zeropg,
              unsigned short* __restrict__ d1, int d1_coff, int d1_ncg,
              unsigned short* __restrict__ d2, int d2_coff, int d2_ncg,
              const unsigned short* __restrict__ xsp, const unsigned short* __restrict__ wiP,
              const float* __restrict__ h0, const float* __restrict__ c0,
              const float* __restrict__ wh, const float* __restrict__ bh,
              const float* __restrict__ bi, unsigned short* __restrict__ eP)
{
    __shared__ __align__(16) char smem[40960];
    if (blockIdx.x < 384)
        cell64_body<NCH>(smem, blockIdx.x, inP, wP, bias, cprev, cout, zeropg,
                         d1, d1_coff, d1_ncg, d2, d2_coff, d2_ncg);
    else if (ATTN)
        attnE_body(smem, blockIdx.x - 384, xsp, wiP, h0, c0, wh, bh, bi, eP);
}

template <int NCH, bool ATTN>
__global__ void __launch_bounds__(256, 2)
mk_cell_alpha(const unsigned short* __restrict__ inP, const unsigned short* __restrict__ wP,
              const float* __restrict__ bias, const float* cprev, float* cout,
              const float* __restrict__ zeropg,
              unsigned short* __restrict__ d1, int d1_coff, int d1_ncg,
              unsigned short* __restrict__ d2, int d2_coff, int d2_ncg,
              const unsigned short* __restrict__ eP, const float* __restrict__ wvv,
              const float* __restrict__ bv, float* __restrict__ alpha,
              unsigned* __restrict__ msl)
{
    __shared__ __align__(16) char smem[40960];
    if (blockIdx.x < 384)
        cell64_body<NCH>(smem, blockIdx.x, inP, wP, bias, cprev, cout, zeropg,
                         d1, d1_coff, d1_ncg, d2, d2_coff, d2_ncg);
    else if (ATTN)
        alpha_body(smem, blockIdx.x - 384, eP, wvv, bv, alpha, msl);
}

// ---------------------------------------------------------------------------
// Merged scale_pack + small_cell5 (inline-scaled): [0,720) scale; [720,1296) small5.
// ---------------------------------------------------------------------------
__global__ void __launch_bounds__(256)
mk_scale_small5(const float* __restrict__ xs_cur, float* __restrict__ xs_nxt,
                unsigned short* __restrict__ xsp,
                const float* __restrict__ alpha, const unsigned* __restrict__ msl,
                int ts,
                const float* __restrict__ h0in, const float* cprev,
                const float* __restrict__ w, const float* __restrict__ bias,
                float* __restrict__ h0out, float* cout,
                unsigned short* __restrict__ pk, int ncg)
{
    __shared__ float z[4][64];
    const int bid = blockIdx.x;
    const float mval = funmap_(msl[0]);
    if (bid < 720) {
        int idx = bid * 256 + threadIdx.x;
        int p = idx % PIX;
        int q = idx / PIX;
        int d = q % ND, bb = q / ND;
        float wgt = __expf(alpha[idx] - mval);
        unsigned short tmp[16];
#pragma unroll
        for (int t = 0; t < TIN; ++t) {
            size_t xi = ((size_t)(bb * TIN + t) * ND + d) * PIX + p;
            float v = xs_cur[xi] * wgt;
            xs_nxt[xi] = v;
            tmp[t] = f2bf(v);
        }
#pragma unroll
        for (int t = TIN; t < 16; ++t) tmp[t] = 0;
        uint4* dst = (uint4*)(xsp + (size_t)idx * 16);
        dst[0] = *(uint4*)&tmp[0];
        dst[1] = *(uint4*)&tmp[8];
    } else {
        int bid2 = bid - 720;
        int bx = bid2 % 144, bb = bid2 / 144;
        const int pxl = threadIdx.x & 63, gate = threadIdx.x >> 6;
        const int p = bx * 64 + pxl;
        const int y = p / 96, x = p - y * 96;
        float acc = bias[gate];
#pragma unroll
        for (int cin = 0; cin < 6; ++cin) {
            const float* wp = w + (gate * 6 + cin) * 9;
#pragma unroll
            for (int ky = 0; ky < 3; ++ky) {
                int gy = y + ky - 1;
                if ((unsigned)gy >= 96u) continue;
#pragma unroll
                for (int kx = 0; kx < 3; ++kx) {
                    int gx = x + kx - 1;
                    if ((unsigned)gx >= 96u) continue;
                    int np = gy * 96 + gx;
                    float v;
                    if (cin < 5) {
                        float raw = xs_cur[((size_t)(bb * TIN + ts) * ND + cin) * PIX + np];
                        v = raw * __expf(alpha[(size_t)(bb * ND + cin) * PIX + np] - mval);
                    } else {
                        v = h0in[bb * PIX + np];
                    }
                    acc = fmaf(wp[ky * 3 + kx], v, acc);
                }
            }
        }
        z[gate][pxl] = acc;
        __syncthreads();
        if (threadIdx.x < 64) {
            int pp = bx * 64 + threadIdx.x;
            int idx = bb * PIX + pp;
            float cn = sigmf_(z[1][threadIdx.x]) * cprev[idx]
                     + sigmf_(z[0][threadIdx.x]) * tanhf_(z[3][threadIdx.x]);
            cout[idx] = cn;
            float h = sigmf_(z[2][threadIdx.x]) * tanhf_(cn);
            h0out[idx] = h;
            pk[((size_t)(bb * ncg) * 9216 + pp) * 8] = f2bf(h);
        }
    }
}

// ---------------------------------------------------------------------------
// Merged decoder dispatch: [0,384) dec1 cell<4>; [384,768) dec0 cell<2>;
// [768,1344) dec2+tcnn.
// ---------------------------------------------------------------------------
template <bool HAS0, bool HAS2>
__global__ void __launch_bounds__(256, 2)
mk_dec(const unsigned short* __restrict__ d1in, const unsigned short* __restrict__ wpd1,
       const float* __restrict__ b1, float* c1, unsigned short* __restrict__ d1out,
       const float* __restrict__ zeropg,
       const unsigned short* __restrict__ d0in, const unsigned short* __restrict__ wpd0,
       const float* __restrict__ b0, float* c2, unsigned short* __restrict__ d0out,
       unsigned short* __restrict__ d1next,
       const unsigned short* __restrict__ d2in,
       const float* __restrict__ hprev, float* c0,
       const unsigned short* __restrict__ wd2m, const float* __restrict__ w2,
       const float* __restrict__ b2,
       const float* __restrict__ tw, const float* __restrict__ tb,
       const float* __restrict__ yprev, float* __restrict__ ynext,
       float* __restrict__ hcarry, float* __restrict__ outp)
{
    __shared__ __align__(16) char smem[40960];
    if (blockIdx.x < 384) {
        cell64_body<4>(smem, blockIdx.x, d1in, wpd1, b1, c1, c1, zeropg,
                       d1out, 64, 16, nullptr, 0, 0);
    } else if (blockIdx.x < 768) {
        if (HAS0)
            cell64_body<2>(smem, blockIdx.x - 384, d0in, wpd0, b0, c2, c2, zeropg,
                           d0out, 0, 8, d1next, 0, 16);
    } else {
        if (HAS2)
            dec2_body(blockIdx.x - 768, d2in, 16, 8, hprev, c0, wd2m, w2, b2,
                      tw, tb, yprev, ynext, hcarry, outp, c0);
    }
}

// standalone wrappers
template <int NCH>
__global__ void __launch_bounds__(256, 2)
cell_k(const unsigned short* __restrict__ inP, const unsigned short* __restrict__ wP,
       const float* __restrict__ bias, const float* cprev, float* cout,
       const float* __restrict__ zeropg,
       unsigned short* __restrict__ d1, int d1_coff, int d1_ncg,
       unsigned short* __restrict__ d2, int d2_coff, int d2_ncg)
{
    __shared__ __align__(16) char smem[40960];
    cell64_body<NCH>(smem, blockIdx.x, inP, wP, bias, cprev, cout, zeropg,
                     d1, d1_coff, d1_ncg, d2, d2_coff, d2_ncg);
}

__global__ void __launch_bounds__(256)
dec2_k(const unsigned short* __restrict__ d2in, const float* __restrict__ hprev,
       float* c0, const unsigned short* __restrict__ wd2m, const float* __restrict__ w2,
       const float* __restrict__ b2, const float* __restrict__ tw, const float* __restrict__ tb,
       const float* __restrict__ yprev, float* __restrict__ ynext,
       float* __restrict__ hcarry, float* __restrict__ outp)
{
    dec2_body(blockIdx.x, d2in, 16, 8, hprev, c0, wd2m, w2, b2,
              tw, tb, yprev, ynext, hcarry, outp, c0);
}

__global__ void __launch_bounds__(256)
attn_e_k(const unsigned short* __restrict__ xsp, const unsigned short* __restrict__ wiP,
         const float* __restrict__ h0, const float* __restrict__ c0,
         const float* __restrict__ wh, const float* __restrict__ bh,
         const float* __restrict__ bi, unsigned short* __restrict__ eP)
{
    __shared__ __align__(16) char smem[33792];
    attnE_body(smem, blockIdx.x, xsp, wiP, h0, c0, wh, bh, bi, eP);
}

__global__ void __launch_bounds__(256)
alpha_k(const unsigned short* __restrict__ eP, const float* __restrict__ wvv,
        const float* __restrict__ bv, float* __restrict__ alpha, unsigned* __restrict__ msl)
{
    __shared__ __align__(16) char smem[1024];
    alpha_body(smem, blockIdx.x, eP, wvv, bv, alpha, msl);
}

// ---------------------------------------------------------------------------
// One-shot prep mega-kernel (gate-interleaved weight packing + xsp + y slice).
// ranges: [0,864) wpe1 | [864,2016) wpe2 | [2016,2592) wpd0 | [2592,3744) wpd1
//         [3744,3780) wd2m | [3780,3800) wiP | [3800,4520) xsp | [4520,5960) slice
// ---------------------------------------------------------------------------
__global__ void __launch_bounds__(256)
prep_kernel(const float* __restrict__ enc_w1, const float* __restrict__ enc_w2,
            const float* __restrict__ dec_w0, const float* __restrict__ dec_w1,
            const float* __restrict__ dec_w2, const float* __restrict__ attn_wi,
            const float* __restrict__ x,
            unsigned short* __restrict__ wpe1, unsigned short* __restrict__ wpe2,
            unsigned short* __restrict__ wpd0, unsigned short* __restrict__ wpd1,
            unsigned short* __restrict__ wd2m, unsigned short* __restrict__ wiP,
            unsigned short* __restrict__ xsp, float* __restrict__ yp)
{
    int gid = blockIdx.x;
    auto wpack = [&](const float* w, unsigned short* wp, int WCIN, int NCH,
                     int coff, int climit, int base) {
        int idx = (gid - base) * 256 + threadIdx.x;
        if (idx >= 9 * NCH * 256 * 32) return;
        int k = idx & 31;
        int ocp = (idx >> 5) & 255;
        int rest = idx >> 13;
        int cc = rest % NCH, tap = rest / NCH;
        int hc = ocp >> 2, gate = ocp & 3;
        int c = cc * 32 + k;
        float v = 0.0f;
        if (c < climit) v = w[((gate * 64 + hc) * WCIN + (c + coff)) * 9 + tap];
        wp[idx] = f2bf(v);
    };
    if (gid < 864) { wpack(enc_w1, wpe1, 65, 3, 0, 65, 0); return; }
    if (gid < 2016) { wpack(enc_w2, wpe2, 128, 4, 0, 128, 864); return; }
    if (gid < 2592) { wpack(dec_w0, wpd0, 65, 2, 1, 64, 2016); return; }
    if (gid < 3744) { wpack(dec_w1, wpd1, 128, 4, 0, 128, 2592); return; }
    if (gid < 3780) {
        int idx = (gid - 3744) * 256 + threadIdx.x;
        if (idx < 9 * 2 * 16 * 32) {
            int k = idx & 31;
            int oc = (idx >> 5) & 15;
            int cc = (idx >> 9) & 1;
            int tap = idx >> 10;
            float v = 0.0f;
            if (oc < 4) v = dec_w2[(oc * 65 + cc * 32 + k) * 9 + tap];
            wd2m[idx] = f2bf(v);
        }
        return;
    }
    if (gid < 3800) {
        int idx = (gid - 3780) * 256 + threadIdx.x;
        if (idx < 5120) {
            int kl = idx & 31, oc = (idx >> 5) & 31, j = idx >> 10;
            int tappos = kl >> 4, ch = kl & 15;
            int tap = 2 * j + tappos;
            float v = 0.0f;
            if (tap < 9 && ch < 10) v = attn_wi[(oc * TIN + ch) * 9 + tap];
            wiP[idx] = f2bf(v);
        }
        return;
    }
    if (gid < 4520) {
        int idx = (gid - 3800) * 256 + threadIdx.x;
        int p = idx % PIX;
        int q = idx / PIX;
        int d = q % ND, bb = q / ND;
        unsigned short tmp[16];
#pragma unroll
        for (int t = 0; t < TIN; ++t)
            tmp[t] = f2bf(x[((size_t)(bb * TIN + t) * ND + d) * PIX + p]);
#pragma unroll
        for (int t = TIN; t < 16; ++t) tmp[t] = 0;
        uint4* dst = (uint4*)(xsp + (size_t)idx * 16);
        dst[0] = *(uint4*)&tmp[0];
        dst[1] = *(uint4*)&tmp[8];
        return;
    }
    {
        int idx = (gid - 4520) * 256 + threadIdx.x;
        int p = idx % PIX;
        int q = idx / PIX;
        yp[idx] = x[(size_t)(q * ND + 0) * PIX + p];
    }
}

// ---------------------------------------------------------------------------
extern "C" void kernel_launch(void* const* d_in, const int* in_sizes, int n_in,
                              void* d_out, int out_size, void* d_ws, size_t ws_size,
                              hipStream_t stream)
{
    const float* x       = (const float*)d_in[0];
    const float* enc_w0  = (const float*)d_in[1];
    const float* enc_b0  = (const float*)d_in[2];
    const float* enc_w1  = (const float*)d_in[3];
    const float* enc_b1  = (const float*)d_in[4];
    const float* enc_w2  = (const float*)d_in[5];
    const float* enc_b2  = (const float*)d_in[6];
    const float* dec_w0  = (const float*)d_in[7];
    const float* dec_b0  = (const float*)d_in[8];
    const float* dec_w1  = (const float*)d_in[9];
    const float* dec_b1  = (const float*)d_in[10];
    const float* dec_w2  = (const float*)d_in[11];
    const float* dec_b2  = (const float*)d_in[12];
    const float* attn_wi = (const float*)d_in[13];
    const float* attn_bi = (const float*)d_in[14];
    const float* attn_wh = (const float*)d_in[15];
    const float* attn_bh = (const float*)d_in[16];
    const float* attn_wv = (const float*)d_in[17];
    const float* attn_bv = (const float*)d_in[18];
    const float* tcnn_w  = (const float*)d_in[19];
    const float* tcnn_b  = (const float*)d_in[20];
    float* out = (float*)d_out;

    char* cur = (char*)d_ws;
    auto alloc = [&](size_t bytes) { char* p = cur; cur += (bytes + 255) & ~(size_t)255; return p; };
    float* xsA  = (float*)alloc((size_t)NB * TIN * ND * PIX * 4);
    float* xsB  = (float*)alloc((size_t)NB * TIN * ND * PIX * 4);
    float* alp  = (float*)alloc((size_t)NB * ND * PIX * 4);
    float* ypa  = (float*)alloc((size_t)NB * TIN * PIX * 4);
    float* ypb  = (float*)alloc((size_t)NB * TIN * PIX * 4);
    unsigned short* wpe1 = (unsigned short*)alloc((size_t)9 * 3 * 256 * 32 * 2);
    unsigned short* wpe2 = (unsigned short*)alloc((size_t)9 * 4 * 256 * 32 * 2);
    unsigned short* wpd0 = (unsigned short*)alloc((size_t)9 * 2 * 256 * 32 * 2);
    unsigned short* wpd1 = (unsigned short*)alloc((size_t)9 * 4 * 256 * 32 * 2);
    unsigned short* wd2m = (unsigned short*)alloc((size_t)9 * 2 * 16 * 32 * 2);
    unsigned short* wiP  = (unsigned short*)alloc(5120 * 2);
    unsigned short* xsp  = (unsigned short*)alloc((size_t)NB * ND * PIX * 16 * 2);
    unsigned short* eP   = (unsigned short*)alloc((size_t)NB * ND * PIX * 32 * 2);
    // ---- contiguous zero-init region ----
    char* zbeg = cur;
    float* h0a  = (float*)alloc(NB * PIX * 4);
    float* h0b  = (float*)alloc(NB * PIX * 4);
    float* c0   = (float*)alloc(NB * PIX * 4);
    float* c1   = (float*)alloc((size_t)NB * HID * PIX * 4);
    float* c2   = (float*)alloc((size_t)NB * HID * PIX * 4);
    const size_t IN1_B = (size_t)NB * 12 * PIX * 8 * 2;
    const size_t IN2_B = (size_t)NB * 16 * PIX * 8 * 2;
    unsigned short* In1a = (unsigned short*)alloc(IN1_B);
    unsigned short* In1b = (unsigned short*)alloc(IN1_B);
    unsigned short* In2a = (unsigned short*)alloc(IN2_B);
    unsigned short* In2b = (unsigned short*)alloc(IN2_B);
    unsigned* mslot = (unsigned*)alloc(256);
    float* zeropg = (float*)alloc(256);
    char* zend = cur;

    hipMemcpyAsync(xsA, x, (size_t)NB * TIN * ND * PIX * 4, hipMemcpyDeviceToDevice, stream);
    hipMemsetAsync(zbeg, 0, (size_t)(zend - zbeg), stream);
    prep_kernel<<<dim3(5960), 256, 0, stream>>>(enc_w1, enc_w2, dec_w0, dec_w1, dec_w2,
                                                attn_wi, x, wpe1, wpe2, wpd0, wpd1,
                                                wd2m, wiP, xsp, ypa);

    dim3 blk(64, 4);
    float *h0 = h0a, *h0n = h0b;
    float *xc = xsA, *xn = xsB;
    unsigned short *i1c = In1a, *i1n = In1b, *i2c = In2a, *i2n = In2b;

    // ---------------- encoder prologue (t=0) ----------------
    attn_e_k<<<dim3(720), blk, 0, stream>>>(xsp, wiP, h0, c0, attn_wh, attn_bh, attn_bi, eP);
    alpha_k<<<dim3(720), blk, 0, stream>>>(eP, attn_wv, attn_bv, alp, mslot + 0);
    mk_scale_small5<<<dim3(1296), 256, 0, stream>>>(xc, xn, xsp, alp, mslot + 0, 0,
                                                    h0, c0, enc_w0, enc_b0, h0n, c0, i1c, 12);
    { float* tmp = h0; h0 = h0n; h0n = tmp; }
    { float* tmp = xc; xc = xn; xn = tmp; }

    // ---------------- encoder main loop ----------------
    for (int t = 0; t < TIN; ++t) {
        const bool hn = (t < TIN - 1);
        unsigned short* e1d1 = hn ? i1n : In2a;
        int e1o = hn ? 1 : 64;
        int e1n = hn ? 12 : 16;
        unsigned short* e2d1 = hn ? i2n : In1a;
        int e2o = hn ? 64 : 0;
        int e2n = hn ? 16 : 8;
        int grid = 384 + (hn ? 720 : 0);

        if (hn)
            mk_cell_attnE<3, true><<<dim3(grid), blk, 0, stream>>>(
                i1c, wpe1, enc_b1, c1, c1, zeropg, e1d1, e1o, e1n, i2c, 0, 16,
                xsp, wiP, h0, c0, attn_wh, attn_bh, attn_bi, eP);
        else
            mk_cell_attnE<3, false><<<dim3(grid), blk, 0, stream>>>(
                i1c, wpe1, enc_b1, c1, c1, zeropg, e1d1, e1o, e1n, i2c, 0, 16,
                xsp, wiP, h0, c0, attn_wh, attn_bh, attn_bi, eP);

        if (hn)
            mk_cell_alpha<4, true><<<dim3(grid), blk, 0, stream>>>(
                i2c, wpe2, enc_b2, c2, c2, zeropg, e2d1, e2o, e2n, nullptr, 0, 0,
                eP, attn_wv, attn_bv, alp, mslot + t + 1);
        else
            mk_cell_alpha<4, false><<<dim3(grid), blk, 0, stream>>>(
                i2c, wpe2, enc_b2, c2, c2, zeropg, e2d1, e2o, e2n, nullptr, 0, 0,
                eP, attn_wv, attn_bv, alp, mslot + t + 1);

        if (hn) {
            mk_scale_small5<<<dim3(1296), 256, 0, stream>>>(xc, xn, xsp, alp, mslot + t + 1,
                                                            t + 1, h0, c0, enc_w0, enc_b0,
                                                            h0n, c0, i1n, 12);
            { float* tmp = h0; h0 = h0n; h0n = tmp; }
            { float* tmp = xc; xc = xn; xn = tmp; }
        }
        { unsigned short* tmp = i1c; i1c = i1n; i1n = tmp; }
        { unsigned short* tmp = i2c; i2c = i2n; i2n = tmp; }
    }

    // ---------------- decoder (pipelined: dec1[t] || dec0[t+1] || dec2[t-1]) --
    float *hc = h0, *hcn = h0n;
    // D0: dec0[0]
    cell_k<2><<<dim3(384), blk, 0, stream>>>(In1a, wpd0, dec_b0, c2, c2, zeropg,
                                             In1b, 0, 8, In2a, 0, 16);
    // D1: dec1[0] || dec0[1]
    mk_dec<true, false><<<dim3(768), blk, 0, stream>>>(
        In2a, wpd1, dec_b1, c1, In2b, zeropg,
        In1b, wpd0, dec_b0, c2, In1a, In2b,
        nullptr, nullptr, nullptr, nullptr, nullptr, nullptr, nullptr, nullptr,
        nullptr, nullptr, nullptr, nullptr);
    // D2: dec1[1] || dec0[2] || dec2[0]
    mk_dec<true, true><<<dim3(1344), blk, 0, stream>>>(
        In2b, wpd1, dec_b1, c1, In2a, zeropg,
        In1a, wpd0, dec_b0, c2, In1b, In2a,
        In2b, hc, c0, wd2m, dec_w2, dec_b2, tcnn_w, tcnn_b,
        ypa, ypb, hcn, out + 0 * PIX);
    // D3: dec1[2] || dec0[3] || dec2[1]
    mk_dec<true, true><<<dim3(1344), blk, 0, stream>>>(
        In2a, wpd1, dec_b1, c1, In2b, zeropg,
        In1b, wpd0, dec_b0, c2, In1a, In2b,
        In2a, hcn, c0, wd2m, dec_w2, dec_b2, tcnn_w, tcnn_b,
        ypb, ypa, hc, out + 1 * PIX);
    // D4: dec1[3] || dec0[4] || dec2[2]
    mk_dec<true, true><<<dim3(1344), blk, 0, stream>>>(
        In2b, wpd1, dec_b1, c1, In2a, zeropg,
        In1a, wpd0, dec_b0, c2, In1b, In2a,
        In2b, hc, c0, wd2m, dec_w2, dec_b2, tcnn_w, tcnn_b,
        ypa, ypb, hcn, out + 2 * PIX);
    // D5: dec1[4] || dec2[3]
    mk_dec<false, true><<<dim3(1344), blk, 0, stream>>>(
        In2a, wpd1, dec_b1, c1, In2b, zeropg,
        nullptr, nullptr, nullptr, nullptr, nullptr, nullptr,
        In2a, hcn, c0, wd2m, dec_w2, dec_b2, tcnn_w, tcnn_b,
        ypb, ypa, hc, out + 3 * PIX);
    // D6: dec2[4]
    dec2_k<<<dim3(576), blk, 0, stream>>>(In2b, hc, c0, wd2m, dec_w2, dec_b2,
                                          tcnn_w, tcnn_b, ypa, ypb, hcn, out + 4 * PIX);
}